// Round 3
// baseline (143.672 us; speedup 1.0000x reference)
//
#include <hip/hip_runtime.h>

typedef __attribute__((ext_vector_type(4))) float f4;
typedef __attribute__((ext_vector_type(4))) float f32x4;
typedef __attribute__((ext_vector_type(8))) __bf16 bf8;
typedef __attribute__((ext_vector_type(8))) unsigned short us8;

#define NB 64
#define LSEQ 40
#define D_DIM 768
#define NPATCH 576
#define SEQ 617
#define K_DIM 768
#define M_DIM (NB * NPATCH)   // 36864
#define A_BYTES 56623104      // M_DIM * K_DIM * 2

static __device__ __forceinline__ unsigned short f2bf(float f) {
    union { float f; unsigned u; } v; v.f = f;
    unsigned r = v.u + 0x7FFFu + ((v.u >> 16) & 1u);
    return (unsigned short)(r >> 16);
}

static __device__ __forceinline__ void gload_lds16(const void* g, void* l) {
    __builtin_amdgcn_global_load_lds(
        (const __attribute__((address_space(1))) unsigned int*)g,
        (__attribute__((address_space(3))) unsigned int*)l,
        16, 0, 0);
}

// ---- convert conv_w (768x768 f32) -> bf16, stored chunk-swizzled ----
// stored[n][blk][c] = logical[n][blk][c ^ (n&7)], chunks of 16B (8 bf16),
// blocks of 128B (64 bf16) along K.
__global__ __launch_bounds__(256) void convert_w(const float* __restrict__ w,
                                                 unsigned short* __restrict__ o) {
    int t = blockIdx.x * 256 + threadIdx.x;   // 73728 threads (768*96 chunks)
    int cs = t % 96, n = t / 96;
    int blk = cs >> 3, c = cs & 7;
    int cl = (blk << 3) | (c ^ (n & 7));      // logical chunk
    const float* s = w + (size_t)n * 768 + cl * 8;
    f4 a = *(const f4*)s;
    f4 b = *(const f4*)(s + 4);
    us8 r;
    r[0]=f2bf(a[0]); r[1]=f2bf(a[1]); r[2]=f2bf(a[2]); r[3]=f2bf(a[3]);
    r[4]=f2bf(b[0]); r[5]=f2bf(b[1]); r[6]=f2bf(b[2]); r[7]=f2bf(b[3]);
    *(us8*)(o + (size_t)n * 768 + cs * 8) = r;
}

// ---- gather pixel patches into bf16 A [M=36864][K=768], chunk-swizzled ----
__global__ __launch_bounds__(256) void convert_patches(const float* __restrict__ px,
                                                       unsigned short* __restrict__ A) {
    int t = blockIdx.x * 256 + threadIdx.x;   // 3538944 threads
    int cs = t % 96, m = t / 96;
    int blk = cs >> 3, c = cs & 7;
    int cl = (blk << 3) | (c ^ (m & 7));      // logical chunk -> k = cl*8
    int k = cl * 8;
    int b = m / 576, p = m % 576;
    int ph = p / 24, pw = p % 24;
    int ch = k >> 8, rr = k & 255, i = rr >> 4, j = rr & 15;  // j in {0,8}
    const float* s = px + ((size_t)(b * 3 + ch) * 384 + ph * 16 + i) * 384 + pw * 16 + j;
    f4 a = *(const f4*)s;
    f4 d = *(const f4*)(s + 4);
    us8 o;
    o[0]=f2bf(a[0]); o[1]=f2bf(a[1]); o[2]=f2bf(a[2]); o[3]=f2bf(a[3]);
    o[4]=f2bf(d[0]); o[5]=f2bf(d[1]); o[6]=f2bf(d[2]); o[7]=f2bf(d[3]);
    *(us8*)(A + (size_t)m * 768 + cs * 8) = o;
}

// ---- text: gather + LayerNorm + mod_type[0], one wave per (b,l) row ----
__global__ __launch_bounds__(256) void text_kernel(
    const int* __restrict__ ids, const int* __restrict__ tti,
    const float* __restrict__ we, const float* __restrict__ pe,
    const float* __restrict__ tke, const float* __restrict__ g,
    const float* __restrict__ bb, const float* __restrict__ mod,
    float* __restrict__ out) {
    int row = blockIdx.x * 4 + (threadIdx.x >> 6);   // 2560 rows
    int lane = threadIdx.x & 63;
    int b = row / 40, l = row % 40;
    const float* wp = we + (size_t)ids[row] * 768;
    const float* pp = pe + l * 768;
    const float* tp = tke + (size_t)tti[row] * 768;
    f4 x[3];
    float s = 0.f, q = 0.f;
#pragma unroll
    for (int j = 0; j < 3; ++j) {
        int d = j * 256 + lane * 4;
        f4 v = *(const f4*)(wp + d);
        f4 v2 = *(const f4*)(pp + d);
        f4 v3 = *(const f4*)(tp + d);
        v = v + v2 + v3;
        x[j] = v;
        s += v[0] + v[1] + v[2] + v[3];
        q += v[0]*v[0] + v[1]*v[1] + v[2]*v[2] + v[3]*v[3];
    }
#pragma unroll
    for (int o = 32; o > 0; o >>= 1) { s += __shfl_xor(s, o); q += __shfl_xor(q, o); }
    float mean = s * (1.0f / 768.0f);
    float var = q * (1.0f / 768.0f) - mean * mean;
    float rstd = rsqrtf(var + 1e-12f);
    float* op = out + ((size_t)b * SEQ + 1 + l) * 768;
#pragma unroll
    for (int j = 0; j < 3; ++j) {
        int d = j * 256 + lane * 4;
        f4 gg = *(const f4*)(g + d);
        f4 bv = *(const f4*)(bb + d);
        f4 mm = *(const f4*)(mod + d);
        f4 r = (x[j] - mean) * rstd * gg + bv + mm;
        *(f4*)(op + d) = r;
    }
}

// ---- patch GEMM: C[m][n] = sum_k A[m][k]*W[n][k], fused epilogue ----
// 2-phase pipeline (T3 minimum): double-buffered LDS, next K-step's
// global_load_lds issued BEFORE current step's ds_read+MFMA, single
// __syncthreads() per step (its implicit vmcnt(0) waits on loads that
// had the whole compute phase to land). Pre-swizzled global A/W keeps
// LDS linear for global_load_lds; ds_read applies matching XOR.
__global__ __launch_bounds__(256) void gemm_patch(
    const __bf16* __restrict__ A, const __bf16* __restrict__ W,
    const float* __restrict__ conv_b, const float* __restrict__ vis_pos,
    const float* __restrict__ mod, float* __restrict__ out) {
    __shared__ __align__(16) __bf16 As[2][128 * 64];
    __shared__ __align__(16) __bf16 Bs[2][128 * 64];
    const int tid = threadIdx.x;
    const int w = tid >> 6, lane = tid & 63;

    // bijective XCD remap: 1728 blocks = 8 XCDs * 216
    int lid = blockIdx.x;
    int gwi = (lid & 7) * 216 + (lid >> 3);
    const int tile_n = (gwi % 6) * 128;
    const int tile_m = (gwi / 6) * 128;
    const int wr = (w >> 1) * 64, wc = (w & 1) * 64;

    f32x4 acc[4][4] = {};
    const char* Ab = (const char*)A;
    const char* Bb = (const char*)W;

    const int uoff_base = (w << 10);
    const int loff_lane = (lane << 4);

    auto STAGE = [&](int buf, int kt) {
        const int k0b = kt * 128;
#pragma unroll
        for (int i = 0; i < 4; ++i) {
            int uoff = i * 4096 + uoff_base;
            int loff = uoff + loff_lane;
            int row = loff >> 7, col = loff & 127;
            gload_lds16(Ab + (size_t)(tile_m + row) * 1536 + k0b + col,
                        (char*)As[buf] + uoff);
            gload_lds16(Bb + (size_t)(tile_n + row) * 1536 + k0b + col,
                        (char*)Bs[buf] + uoff);
        }
    };

    STAGE(0, 0);
    __syncthreads();   // drain prologue stage

    int cur = 0;
    const int rsel = lane & 15;
    const int hk = lane >> 4;          // 16B chunk within 64B k-slice

    for (int kt = 0; kt < 12; ++kt) {
        if (kt < 11) STAGE(cur ^ 1, kt + 1);   // prefetch next K-step

        bf8 a[4][2], b[4][2];
#pragma unroll
        for (int mi = 0; mi < 4; ++mi) {
            int r = wr + mi * 16 + rsel;
#pragma unroll
            for (int ks = 0; ks < 2; ++ks) {
                int cst = (ks * 4 + hk) ^ (r & 7);
                a[mi][ks] = *(const bf8*)((const char*)As[cur] + r * 128 + cst * 16);
            }
        }
#pragma unroll
        for (int ni = 0; ni < 4; ++ni) {
            int r = wc + ni * 16 + rsel;
#pragma unroll
            for (int ks = 0; ks < 2; ++ks) {
                int cst = (ks * 4 + hk) ^ (r & 7);
                b[ni][ks] = *(const bf8*)((const char*)Bs[cur] + r * 128 + cst * 16);
            }
        }
#pragma unroll
        for (int mi = 0; mi < 4; ++mi)
#pragma unroll
            for (int ni = 0; ni < 4; ++ni) {
                acc[mi][ni] = __builtin_amdgcn_mfma_f32_16x16x32_bf16(
                    a[mi][0], b[ni][0], acc[mi][ni], 0, 0, 0);
                acc[mi][ni] = __builtin_amdgcn_mfma_f32_16x16x32_bf16(
                    a[mi][1], b[ni][1], acc[mi][ni], 0, 0, 0);
            }
        if (kt < 11) __syncthreads();  // waits vmcnt(0): next stage landed
        cur ^= 1;
    }

    const int lr = (lane >> 4) * 4;
    const int lc = lane & 15;
#pragma unroll
    for (int mi = 0; mi < 4; ++mi) {
#pragma unroll
        for (int r = 0; r < 4; ++r) {
            int gm = tile_m + wr + mi * 16 + lr + r;
            int bimg = gm / 576, p = gm % 576;
            size_t orow = (size_t)bimg * SEQ + 1 + LSEQ + p;
#pragma unroll
            for (int ni = 0; ni < 4; ++ni) {
                int gn = tile_n + wc + ni * 16 + lc;
                float v = acc[mi][ni][r] + conv_b[gn] +
                          vis_pos[(size_t)(p + 1) * 768 + gn] + mod[768 + gn];
                out[orow * 768 + gn] = v;
            }
        }
    }
}

// ---- CLS rows + masks ----
__global__ __launch_bounds__(256) void cls_masks(const float* __restrict__ cls,
                                                 const int* __restrict__ am,
                                                 float* __restrict__ out) {
    int t = blockIdx.x * 256 + threadIdx.x;
    if (t < NB * 768) {
        int b = t / 768, d = t % 768;
        out[(size_t)b * SEQ * 768 + d] = cls[d];
    } else if (t < NB * 768 + NB * SEQ) {
        int i = t - NB * 768;
        int b = i / SEQ, s = i % SEQ;
        float v = 1.0f;
        if (s >= 1 && s <= LSEQ) v = (float)am[b * LSEQ + s - 1];
        out[(size_t)NB * SEQ * 768 + i] = v;
    }
}

extern "C" void kernel_launch(void* const* d_in, const int* in_sizes, int n_in,
                              void* d_out, int out_size, void* d_ws, size_t ws_size,
                              hipStream_t stream) {
    const int*   ids  = (const int*)d_in[0];
    const int*   am   = (const int*)d_in[1];
    const int*   tti  = (const int*)d_in[2];
    const float* px   = (const float*)d_in[3];
    const float* we   = (const float*)d_in[5];
    const float* pe   = (const float*)d_in[6];
    const float* tke  = (const float*)d_in[7];
    const float* lng  = (const float*)d_in[8];
    const float* lnb  = (const float*)d_in[9];
    const float* cw   = (const float*)d_in[10];
    const float* cb   = (const float*)d_in[11];
    const float* cls  = (const float*)d_in[12];
    const float* vpos = (const float*)d_in[13];
    const float* mod  = (const float*)d_in[14];
    float* out = (float*)d_out;

    __bf16* Abf = (__bf16*)d_ws;
    __bf16* Wbf = (__bf16*)((char*)d_ws + A_BYTES);

    convert_w<<<288, 256, 0, stream>>>(cw, (unsigned short*)Wbf);
    convert_patches<<<13824, 256, 0, stream>>>(px, (unsigned short*)Abf);
    text_kernel<<<640, 256, 0, stream>>>(ids, tti, we, pe, tke, lng, lnb, mod, out);
    gemm_patch<<<1728, 256, 0, stream>>>(Abf, Wbf, cb, vpos, mod, out);
    cls_masks<<<347, 256, 0, stream>>>(cls, am, out);
}

// Round 4
// 108.201 us; speedup vs baseline: 1.3278x; 1.3278x over previous
//
#include <hip/hip_runtime.h>

typedef __attribute__((ext_vector_type(4))) float f4;
typedef __attribute__((ext_vector_type(4))) float f32x4;
typedef __attribute__((ext_vector_type(8))) __bf16 bf8;
typedef __attribute__((ext_vector_type(8))) unsigned short us8;

#define NB 64
#define LSEQ 40
#define D_DIM 768
#define NPATCH 576
#define SEQ 617
#define K_DIM 768
#define M_DIM (NB * NPATCH)   // 36864
#define A_BYTES 56623104      // M_DIM * K_DIM * 2
#define GEMM_LDS 131072

static __device__ __forceinline__ unsigned short f2bf(float f) {
    union { float f; unsigned u; } v; v.f = f;
    unsigned r = v.u + 0x7FFFu + ((v.u >> 16) & 1u);
    return (unsigned short)(r >> 16);
}

static __device__ __forceinline__ void gload_lds16(const void* g, void* l) {
    __builtin_amdgcn_global_load_lds(
        (const __attribute__((address_space(1))) unsigned int*)g,
        (__attribute__((address_space(3))) unsigned int*)l,
        16, 0, 0);
}

// ---- convert conv_w (768x768 f32) -> bf16, stored chunk-swizzled ----
// stored[n][blk][c] = logical[n][blk][c ^ (n&7)], chunks of 16B (8 bf16),
// blocks of 128B (64 bf16) along K.
__global__ __launch_bounds__(256) void convert_w(const float* __restrict__ w,
                                                 unsigned short* __restrict__ o) {
    int t = blockIdx.x * 256 + threadIdx.x;   // 73728 threads (768*96 chunks)
    int cs = t % 96, n = t / 96;
    int blk = cs >> 3, c = cs & 7;
    int cl = (blk << 3) | (c ^ (n & 7));      // logical chunk
    const float* s = w + (size_t)n * 768 + cl * 8;
    f4 a = *(const f4*)s;
    f4 b = *(const f4*)(s + 4);
    us8 r;
    r[0]=f2bf(a[0]); r[1]=f2bf(a[1]); r[2]=f2bf(a[2]); r[3]=f2bf(a[3]);
    r[4]=f2bf(b[0]); r[5]=f2bf(b[1]); r[6]=f2bf(b[2]); r[7]=f2bf(b[3]);
    *(us8*)(o + (size_t)n * 768 + cs * 8) = r;
}

// ---- gather pixel patches into bf16 A [M=36864][K=768], chunk-swizzled ----
__global__ __launch_bounds__(256) void convert_patches(const float* __restrict__ px,
                                                       unsigned short* __restrict__ A) {
    int t = blockIdx.x * 256 + threadIdx.x;   // 3538944 threads
    int cs = t % 96, m = t / 96;
    int blk = cs >> 3, c = cs & 7;
    int cl = (blk << 3) | (c ^ (m & 7));      // logical chunk -> k = cl*8
    int k = cl * 8;
    int b = m / 576, p = m % 576;
    int ph = p / 24, pw = p % 24;
    int ch = k >> 8, rr = k & 255, i = rr >> 4, j = rr & 15;  // j in {0,8}
    const float* s = px + ((size_t)(b * 3 + ch) * 384 + ph * 16 + i) * 384 + pw * 16 + j;
    f4 a = *(const f4*)s;
    f4 d = *(const f4*)(s + 4);
    us8 o;
    o[0]=f2bf(a[0]); o[1]=f2bf(a[1]); o[2]=f2bf(a[2]); o[3]=f2bf(a[3]);
    o[4]=f2bf(d[0]); o[5]=f2bf(d[1]); o[6]=f2bf(d[2]); o[7]=f2bf(d[3]);
    *(us8*)(A + (size_t)m * 768 + cs * 8) = o;
}

// ---- text: gather + LayerNorm + mod_type[0], one wave per (b,l) row ----
__global__ __launch_bounds__(256) void text_kernel(
    const int* __restrict__ ids, const int* __restrict__ tti,
    const float* __restrict__ we, const float* __restrict__ pe,
    const float* __restrict__ tke, const float* __restrict__ g,
    const float* __restrict__ bb, const float* __restrict__ mod,
    float* __restrict__ out) {
    int row = blockIdx.x * 4 + (threadIdx.x >> 6);   // 2560 rows
    int lane = threadIdx.x & 63;
    int b = row / 40, l = row % 40;
    const float* wp = we + (size_t)ids[row] * 768;
    const float* pp = pe + l * 768;
    const float* tp = tke + (size_t)tti[row] * 768;
    f4 x[3];
    float s = 0.f, q = 0.f;
#pragma unroll
    for (int j = 0; j < 3; ++j) {
        int d = j * 256 + lane * 4;
        f4 v = *(const f4*)(wp + d);
        f4 v2 = *(const f4*)(pp + d);
        f4 v3 = *(const f4*)(tp + d);
        v = v + v2 + v3;
        x[j] = v;
        s += v[0] + v[1] + v[2] + v[3];
        q += v[0]*v[0] + v[1]*v[1] + v[2]*v[2] + v[3]*v[3];
    }
#pragma unroll
    for (int o = 32; o > 0; o >>= 1) { s += __shfl_xor(s, o); q += __shfl_xor(q, o); }
    float mean = s * (1.0f / 768.0f);
    float var = q * (1.0f / 768.0f) - mean * mean;
    float rstd = rsqrtf(var + 1e-12f);
    float* op = out + ((size_t)b * SEQ + 1 + l) * 768;
#pragma unroll
    for (int j = 0; j < 3; ++j) {
        int d = j * 256 + lane * 4;
        f4 gg = *(const f4*)(g + d);
        f4 bv = *(const f4*)(bb + d);
        f4 mm = *(const f4*)(mod + d);
        f4 r = (x[j] - mean) * rstd * gg + bv + mm;
        *(f4*)(op + d) = r;
    }
}

// ---- patch GEMM: 256x256 tile, BK=64, 512 thr (8 waves 2Mx4N), dbuf LDS ----
// Per K-tile: STAGE_A(next) -> read a[0:4],b[0:4] -> STAGE_B(next) ->
// 32 MFMA (Q0) -> read a[4:8] -> 32 MFMA (Q1) -> vmcnt(0) + s_barrier.
// Sync edges: buffer p^1 staged at tile t was last READ at tile t-1 (reads
// complete before t-1's end barrier, which precedes the stage). Loads for
// tile t+1's buffer drain at t's end vmcnt(0) (covered by ~64 MFMAs),
// barrier makes it block-wide. Pre-swizzled global A/W keeps LDS linear
// for global_load_lds; ds_read applies matching chunk-XOR -> conflict-free.
__global__ __launch_bounds__(512, 2) void gemm_patch(
    const __bf16* __restrict__ A, const __bf16* __restrict__ W,
    const float* __restrict__ conv_b, const float* __restrict__ vis_pos,
    const float* __restrict__ mod, float* __restrict__ out) {
    extern __shared__ __align__(16) char smem[];   // 128 KB: A[2][32K] B[2][32K]
    const int tid = threadIdx.x;
    const int w = tid >> 6, lane = tid & 63;

    // bijective XCD remap: 432 blocks = 8 XCDs * 54
    int lid = blockIdx.x;
    int gwi = (lid & 7) * 54 + (lid >> 3);
    const int tile_n = (gwi % 3) * 256;
    const int tile_m = (gwi / 3) * 256;
    const int wm = w >> 2, wn = w & 3;
    const int wr = wm * 128, wc = wn * 64;

    f32x4 acc[8][4] = {};
    const char* Ab = (const char*)A;
    const char* Bb = (const char*)W;

    auto STAGE_A = [&](int p, int kt) {
        const int k0b = kt * 128;
        char* dst = smem + p * 32768;
#pragma unroll
        for (int i = 0; i < 4; ++i) {
            int uoff = (w << 10) + i * 8192;       // wave-uniform LDS base
            int loff = uoff + (lane << 4);
            int row = loff >> 7, col = loff & 127;
            gload_lds16(Ab + (size_t)(tile_m + row) * 1536 + k0b + col, dst + uoff);
        }
    };
    auto STAGE_B = [&](int p, int kt) {
        const int k0b = kt * 128;
        char* dst = smem + 65536 + p * 32768;
#pragma unroll
        for (int i = 0; i < 4; ++i) {
            int uoff = (w << 10) + i * 8192;
            int loff = uoff + (lane << 4);
            int row = loff >> 7, col = loff & 127;
            gload_lds16(Bb + (size_t)(tile_n + row) * 1536 + k0b + col, dst + uoff);
        }
    };

    STAGE_A(0, 0);
    STAGE_B(0, 0);
    asm volatile("s_waitcnt vmcnt(0)" ::: "memory");
    __builtin_amdgcn_sched_barrier(0);
    __builtin_amdgcn_s_barrier();
    __builtin_amdgcn_sched_barrier(0);

    const int rsel = lane & 15;
    const int hk = lane >> 4;          // 16B chunk within 64B k-slice

    for (int kt = 0; kt < 12; ++kt) {
        const int p = kt & 1;
        const char* Al = smem + p * 32768;
        const char* Bl = smem + 65536 + p * 32768;

        if (kt < 11) STAGE_A(p ^ 1, kt + 1);

        bf8 a0[4][2], b0[4][2];
#pragma unroll
        for (int mi = 0; mi < 4; ++mi) {
            int r = wr + mi * 16 + rsel;
#pragma unroll
            for (int ks = 0; ks < 2; ++ks) {
                int cst = (ks * 4 + hk) ^ (r & 7);
                a0[mi][ks] = *(const bf8*)(Al + r * 128 + cst * 16);
            }
        }
#pragma unroll
        for (int ni = 0; ni < 4; ++ni) {
            int r = wc + ni * 16 + rsel;
#pragma unroll
            for (int ks = 0; ks < 2; ++ks) {
                int cst = (ks * 4 + hk) ^ (r & 7);
                b0[ni][ks] = *(const bf8*)(Bl + r * 128 + cst * 16);
            }
        }

        if (kt < 11) STAGE_B(p ^ 1, kt + 1);

#pragma unroll
        for (int mi = 0; mi < 4; ++mi)
#pragma unroll
            for (int ni = 0; ni < 4; ++ni) {
                acc[mi][ni] = __builtin_amdgcn_mfma_f32_16x16x32_bf16(
                    a0[mi][0], b0[ni][0], acc[mi][ni], 0, 0, 0);
                acc[mi][ni] = __builtin_amdgcn_mfma_f32_16x16x32_bf16(
                    a0[mi][1], b0[ni][1], acc[mi][ni], 0, 0, 0);
            }

        bf8 a1[4][2];
#pragma unroll
        for (int mi = 0; mi < 4; ++mi) {
            int r = wr + 64 + mi * 16 + rsel;
#pragma unroll
            for (int ks = 0; ks < 2; ++ks) {
                int cst = (ks * 4 + hk) ^ (r & 7);
                a1[mi][ks] = *(const bf8*)(Al + r * 128 + cst * 16);
            }
        }
#pragma unroll
        for (int mi = 0; mi < 4; ++mi)
#pragma unroll
            for (int ni = 0; ni < 4; ++ni) {
                acc[4 + mi][ni] = __builtin_amdgcn_mfma_f32_16x16x32_bf16(
                    a1[mi][0], b0[ni][0], acc[4 + mi][ni], 0, 0, 0);
                acc[4 + mi][ni] = __builtin_amdgcn_mfma_f32_16x16x32_bf16(
                    a1[mi][1], b0[ni][1], acc[4 + mi][ni], 0, 0, 0);
            }

        if (kt < 11) {
            asm volatile("s_waitcnt vmcnt(0)" ::: "memory");
            __builtin_amdgcn_sched_barrier(0);
            __builtin_amdgcn_s_barrier();
            __builtin_amdgcn_sched_barrier(0);
        }
    }

    const int lr = (lane >> 4) * 4;
    const int lc = lane & 15;
#pragma unroll
    for (int mi = 0; mi < 8; ++mi) {
#pragma unroll
        for (int r = 0; r < 4; ++r) {
            int gm = tile_m + wr + mi * 16 + lr + r;
            int bimg = gm / 576, pp = gm % 576;
            size_t orow = (size_t)bimg * SEQ + 1 + LSEQ + pp;
#pragma unroll
            for (int ni = 0; ni < 4; ++ni) {
                int gn = tile_n + wc + ni * 16 + lc;
                float v = acc[mi][ni][r] + conv_b[gn] +
                          vis_pos[(size_t)(pp + 1) * 768 + gn] + mod[768 + gn];
                out[orow * 768 + gn] = v;
            }
        }
    }
}

// ---- CLS rows + masks ----
__global__ __launch_bounds__(256) void cls_masks(const float* __restrict__ cls,
                                                 const int* __restrict__ am,
                                                 float* __restrict__ out) {
    int t = blockIdx.x * 256 + threadIdx.x;
    if (t < NB * 768) {
        int b = t / 768, d = t % 768;
        out[(size_t)b * SEQ * 768 + d] = cls[d];
    } else if (t < NB * 768 + NB * SEQ) {
        int i = t - NB * 768;
        int b = i / SEQ, s = i % SEQ;
        float v = 1.0f;
        if (s >= 1 && s <= LSEQ) v = (float)am[b * LSEQ + s - 1];
        out[(size_t)NB * SEQ * 768 + i] = v;
    }
}

extern "C" void kernel_launch(void* const* d_in, const int* in_sizes, int n_in,
                              void* d_out, int out_size, void* d_ws, size_t ws_size,
                              hipStream_t stream) {
    const int*   ids  = (const int*)d_in[0];
    const int*   am   = (const int*)d_in[1];
    const int*   tti  = (const int*)d_in[2];
    const float* px   = (const float*)d_in[3];
    const float* we   = (const float*)d_in[5];
    const float* pe   = (const float*)d_in[6];
    const float* tke  = (const float*)d_in[7];
    const float* lng  = (const float*)d_in[8];
    const float* lnb  = (const float*)d_in[9];
    const float* cw   = (const float*)d_in[10];
    const float* cb   = (const float*)d_in[11];
    const float* cls  = (const float*)d_in[12];
    const float* vpos = (const float*)d_in[13];
    const float* mod  = (const float*)d_in[14];
    float* out = (float*)d_out;

    __bf16* Abf = (__bf16*)d_ws;
    __bf16* Wbf = (__bf16*)((char*)d_ws + A_BYTES);

    hipFuncSetAttribute((const void*)gemm_patch,
                        hipFuncAttributeMaxDynamicSharedMemorySize, GEMM_LDS);

    convert_w<<<288, 256, 0, stream>>>(cw, (unsigned short*)Wbf);
    convert_patches<<<13824, 256, 0, stream>>>(px, (unsigned short*)Abf);
    text_kernel<<<640, 256, 0, stream>>>(ids, tti, we, pe, tke, lng, lnb, mod, out);
    gemm_patch<<<432, 512, GEMM_LDS, stream>>>(Abf, Wbf, cb, vpos, mod, out);
    cls_masks<<<347, 256, 0, stream>>>(cls, am, out);
}